// Round 16
// baseline (168.356 us; speedup 1.0000x reference)
//
#include <hip/hip_runtime.h>
#include <hip/hip_bf16.h>

#define N_ENT    100000
#define NUM_REL  400
#define DIM      128
#define NUM_EDGES 800000
#define E_HALF   400000
#define N_RB     6250          // N_ENT/16 rowblocks
#define CAP      24            // bucket capacity; P(Poisson(4) > 24) ~ 1.6e-12

using short8 = __attribute__((ext_vector_type(8))) short;
using f32x4  = __attribute__((ext_vector_type(4))) float;

__device__ __forceinline__ float bf_lo(unsigned u) { return __uint_as_float(u << 16); }
__device__ __forceinline__ float bf_hi(unsigned u) { return __uint_as_float(u & 0xffff0000u); }
__device__ __forceinline__ unsigned short f2bf(float f) {
    unsigned u = __float_as_uint(f);
    u = u + 0x7fffu + ((u >> 16) & 1u);   // RNE
    return (unsigned short)(u >> 16);
}
__device__ __forceinline__ unsigned pack2bf(float a, float b) {
    return (unsigned)f2bf(a) | ((unsigned)f2bf(b) << 16);
}

// ---------------- mega: fill_vec4 | xb (4 chunks/thread) | wtfrag | rb16 | cvec | rel ----------------
#define FB_FILL 782                    // 782*256 threads, 4 CONSECUTIVE edges each (int4 loads)
#define FB_XB   (FB_FILL + 1563)       // 1563*256*4 chunks >= 1.6M
#define FB_WT   (FB_XB + 24)
#define FB_RB   (FB_WT + 25)
#define FB_CV   (FB_RB + 1)
#define FB_REL  (FB_CV + 200)
__global__ __launch_bounds__(256) void mega_kernel(const int* __restrict__ rows,
                                                   const int* __restrict__ cols,
                                                   const int* __restrict__ et,
                                                   const float* __restrict__ x,
                                                   const float* __restrict__ w_in,
                                                   const float* __restrict__ w_out,
                                                   const float* __restrict__ w_loop,
                                                   const float* __restrict__ r,
                                                   const float* __restrict__ loop_rel,
                                                   const float* __restrict__ w_rel,
                                                   int* __restrict__ cursor,
                                                   unsigned* __restrict__ recs,
                                                   uint4* __restrict__ xb4,
                                                   uint4* __restrict__ wtfrag,
                                                   uint4* __restrict__ rb16,
                                                   float* __restrict__ cvec,
                                                   float* __restrict__ r_out) {
    int b = blockIdx.x;
    int t = threadIdx.x;
    if (b < FB_FILL) {
        int ti = b * 256 + t;                  // quad index
        if (ti < NUM_EDGES / 4) {
            int e0 = ti * 4;                   // E_HALF % 4 == 0: quad never straddles halves
            int4 rw = *(const int4*)(rows + e0);
            int4 cl = *(const int4*)(cols + e0);
            int4 ty = *(const int4*)(et + e0);
            int hb2 = (e0 >= E_HALF) ? N_ENT : 0;
            int g0 = hb2 + rw.x, g1 = hb2 + rw.y, g2 = hb2 + rw.z, g3 = hb2 + rw.w;
            int p0 = atomicAdd(&cursor[g0], 1);
            int p1 = atomicAdd(&cursor[g1], 1);
            int p2 = atomicAdd(&cursor[g2], 1);
            int p3 = atomicAdd(&cursor[g3], 1);
            if (p0 < CAP) recs[(size_t)g0 * CAP + p0] = (unsigned)cl.x | ((unsigned)ty.x << 17);
            if (p1 < CAP) recs[(size_t)g1 * CAP + p1] = (unsigned)cl.y | ((unsigned)ty.y << 17);
            if (p2 < CAP) recs[(size_t)g2 * CAP + p2] = (unsigned)cl.z | ((unsigned)ty.z << 17);
            if (p3 < CAP) recs[(size_t)g3 * CAP + p3] = (unsigned)cl.w | ((unsigned)ty.w << 17);
        }
    } else if (b < FB_XB) {
        // 4 consecutive 64B-chunks per thread: 8 loads in flight, then 4 stores
        int i0 = ((b - FB_FILL) * 256 + t) * 4;
        float4 f[8];
        #pragma unroll
        for (int k = 0; k < 4; ++k) {
            int i = i0 + k;
            bool ok = i < N_ENT * 16;
            const float* p = x + (ok ? ((size_t)(i >> 4) * DIM + (i & 15) * 8) : 0);
            f[2 * k]     = *(const float4*)p;
            f[2 * k + 1] = *(const float4*)(p + 4);
        }
        #pragma unroll
        for (int k = 0; k < 4; ++k) {
            int i = i0 + k;
            if (i < N_ENT * 16) {
                uint4 o;
                o.x = pack2bf(f[2 * k].x, f[2 * k].y);
                o.y = pack2bf(f[2 * k].z, f[2 * k].w);
                o.z = pack2bf(f[2 * k + 1].x, f[2 * k + 1].y);
                o.w = pack2bf(f[2 * k + 1].z, f[2 * k + 1].w);
                xb4[i] = o;
            }
        }
    } else if (b < FB_WT) {
        int j = (b - FB_XB) * 256 + t;
        if (j < 8 * 12 * 64) {
            int lane = j & 63;
            int kb = (j >> 6) % 12;
            int nblk = j / 768;
            int n = nblk * 16 + (lane & 15);
            int s = kb >> 2;
            int klo = (kb & 3) * 32 + (lane >> 4) * 8;    // 0..127 within slice
            const float* W = (s == 0) ? w_in : (s == 1) ? w_out : w_loop;
            float v[8];
            #pragma unroll
            for (int e = 0; e < 8; ++e) v[e] = W[(klo + e) * DIM + n];
            uint4 o;
            o.x = pack2bf(v[0], v[1]);
            o.y = pack2bf(v[2], v[3]);
            o.z = pack2bf(v[4], v[5]);
            o.w = pack2bf(v[6], v[7]);
            wtfrag[j] = o;
        }
    } else if (b < FB_RB) {
        int k = (b - FB_WT) * 256 + t;
        if (k < NUM_REL * 16) {
            const float* p = r + (size_t)(k >> 4) * DIM + (k & 15) * 8;
            float4 f0 = *(const float4*)p;
            float4 f1 = *(const float4*)(p + 4);
            uint4 o;
            o.x = pack2bf(f0.x, f0.y);
            o.y = pack2bf(f0.z, f0.w);
            o.z = pack2bf(f1.x, f1.y);
            o.w = pack2bf(f1.z, f1.w);
            rb16[k] = o;
        }
    } else if (b < FB_CV) {
        if (t < 128) {
            float acc = 0.0f;
            #pragma unroll 8
            for (int k = 0; k < DIM; ++k)
                acc += loop_rel[k] * w_loop[k * DIM + t];
            cvec[t] = acc;
        }
    } else {
        int row = (b - FB_CV) * 2 + (t >> 7);
        int col = t & 127;
        const float* rr = r + (size_t)row * DIM;
        float acc = 0.0f;
        #pragma unroll 8
        for (int k = 0; k < DIM; ++k)
            acc += rr[k] * w_rel[k * DIM + col];
        r_out[(size_t)row * DIM + col] = acc;
    }
}

// ---------------- gather-aggregate -> aggfrag (r13-exact: 16 lanes/segment) ----------------
#define ACC8(X, V, NRM)                                        \
    acc[0] += (NRM) * (bf_lo((X).x) - bf_lo((V).x));           \
    acc[1] += (NRM) * (bf_hi((X).x) - bf_hi((V).x));           \
    acc[2] += (NRM) * (bf_lo((X).y) - bf_lo((V).y));           \
    acc[3] += (NRM) * (bf_hi((X).y) - bf_hi((V).y));           \
    acc[4] += (NRM) * (bf_lo((X).z) - bf_lo((V).z));           \
    acc[5] += (NRM) * (bf_hi((X).z) - bf_hi((V).z));           \
    acc[6] += (NRM) * (bf_lo((X).w) - bf_lo((V).w));           \
    acc[7] += (NRM) * (bf_hi((X).w) - bf_hi((V).w));

__global__ __launch_bounds__(256) void gather_agg_kernel(const int* __restrict__ cursor,
                                                         const unsigned* __restrict__ recs,
                                                         const unsigned short* __restrict__ xb,
                                                         const unsigned short* __restrict__ rb16,
                                                         uint4* __restrict__ aggfrag) {
    int gid = blockIdx.x * 256 + threadIdx.x;
    int g = gid >> 4;
    if (g >= 2 * N_ENT) return;
    int c = gid & 15;                    // lane covers 16 B = 8 bf16 (k = c*8..c*8+7)
    int dg = cursor[g];
    int hb = (g >= N_ENT) ? N_ENT : 0;   // deg base for this half
    float acc[8] = {0.f, 0.f, 0.f, 0.f, 0.f, 0.f, 0.f, 0.f};
    if (dg > 0) {
        int dgc = dg < CAP ? dg : CAP;
        float dgi = rsqrtf((float)dg);
        const unsigned* rb = recs + (size_t)g * CAP;
        int e = 0;
        for (; e + 4 <= dgc; e += 4) {
            unsigned r0 = rb[e], r1 = rb[e + 1], r2 = rb[e + 2], r3 = rb[e + 3];
            int c0 = r0 & 0x1ffff, t0 = r0 >> 17;
            int c1 = r1 & 0x1ffff, t1 = r1 >> 17;
            int c2 = r2 & 0x1ffff, t2 = r2 >> 17;
            int c3 = r3 & 0x1ffff, t3 = r3 >> 17;
            int d0 = cursor[hb + c0];
            int d1 = cursor[hb + c1];
            int d2 = cursor[hb + c2];
            int d3 = cursor[hb + c3];
            uint4 x0 = ((const uint4*)(xb + (size_t)c0 * DIM))[c];
            uint4 v0 = ((const uint4*)(rb16 + (size_t)t0 * DIM))[c];
            uint4 x1 = ((const uint4*)(xb + (size_t)c1 * DIM))[c];
            uint4 v1 = ((const uint4*)(rb16 + (size_t)t1 * DIM))[c];
            uint4 x2 = ((const uint4*)(xb + (size_t)c2 * DIM))[c];
            uint4 v2 = ((const uint4*)(rb16 + (size_t)t2 * DIM))[c];
            uint4 x3 = ((const uint4*)(xb + (size_t)c3 * DIM))[c];
            uint4 v3 = ((const uint4*)(rb16 + (size_t)t3 * DIM))[c];
            float n0 = (d0 > 0) ? dgi * rsqrtf((float)d0) : 0.0f;
            float n1 = (d1 > 0) ? dgi * rsqrtf((float)d1) : 0.0f;
            float n2 = (d2 > 0) ? dgi * rsqrtf((float)d2) : 0.0f;
            float n3 = (d3 > 0) ? dgi * rsqrtf((float)d3) : 0.0f;
            ACC8(x0, v0, n0)
            ACC8(x1, v1, n1)
            ACC8(x2, v2, n2)
            ACC8(x3, v3, n3)
        }
        for (; e < dgc; ++e) {
            unsigned rA = rb[e];
            int cA = rA & 0x1ffff, tA = rA >> 17;
            int dA = cursor[hb + cA];
            uint4 xA = ((const uint4*)(xb + (size_t)cA * DIM))[c];
            uint4 vA = ((const uint4*)(rb16 + (size_t)tA * DIM))[c];
            float nA = (dA > 0) ? dgi * rsqrtf((float)dA) : 0.0f;
            ACC8(xA, vA, nA)
        }
    }
    uint4 o;
    o.x = pack2bf(acc[0], acc[1]);
    o.y = pack2bf(acc[2], acc[3]);
    o.z = pack2bf(acc[4], acc[5]);
    o.w = pack2bf(acc[6], acc[7]);
    // fragment-order store: rowblk=g>>4, kq=c>>2, ksub=c&3, lr=g&15
    aggfrag[(((g >> 4) * 4 + (c >> 2)) * 64) + (c & 3) * 16 + (g & 15)] = o;
}

// ---------------- MFMA GEMM, fragment-direct, split-K2, hoisted A-loads ----------------
// out = tanh((aggA@Win + aggB@Wout + x@Wloop - cvec)/3 + bias)
// M=100000, N=128, K=384. Block = 32 rows x 128 cols, 4 waves (wn, kh).
__global__ __launch_bounds__(256) void mfma_gemm_kernel(const uint4* __restrict__ aggfrag,
                                                        const unsigned short* __restrict__ xb,
                                                        const uint4* __restrict__ wtfrag,
                                                        const float* __restrict__ bias,
                                                        const float* __restrict__ cvec,
                                                        float* __restrict__ out) {
    __shared__ float plds[2][32][65];      // 16.6 KB, stride-65 rows (bank-safe)

    int tid = threadIdx.x;
    int wave = tid >> 6;
    int lane = tid & 63;
    int wn = wave & 1;                     // col half
    int kh = wave >> 1;                    // K half
    int lr = lane & 15;
    int ks = lane >> 4;                    // 0..3
    int rbb = blockIdx.x * 2;              // 2 rowblocks of 16 (exact: 3125*32=100000)
    int row0 = blockIdx.x * 32;

    // ---- hoist ALL A-fragment loads (12 uint4, statically indexed) ----
    uint4 ua[2][6];
    #pragma unroll
    for (int j = 0; j < 6; ++j) {
        int kb = kh * 6 + j;
        int s = kb >> 2, kq = kb & 3;      // wave-uniform
        #pragma unroll
        for (int mi = 0; mi < 2; ++mi) {
            if (s < 2) {
                ua[mi][j] = aggfrag[((size_t)(rbb + mi + s * N_RB) * 4 + kq) * 64 + lane];
            } else {
                int row = (rbb + mi) * 16 + lr;
                ua[mi][j] = *(const uint4*)(xb + (size_t)row * DIM + kq * 32 + ks * 8);
            }
        }
    }

    f32x4 acc[2][4];
    #pragma unroll
    for (int mi = 0; mi < 2; ++mi)
        #pragma unroll
        for (int ni = 0; ni < 4; ++ni)
            acc[mi][ni] = (f32x4){0.f, 0.f, 0.f, 0.f};

    #pragma unroll
    for (int j = 0; j < 6; ++j) {
        int kb = kh * 6 + j;
        short8 b[4];
        #pragma unroll
        for (int ni = 0; ni < 4; ++ni) {
            uint4 u = wtfrag[((wn * 4 + ni) * 12 + kb) * 64 + lane];
            b[ni] = *(short8*)&u;
        }
        #pragma unroll
        for (int mi = 0; mi < 2; ++mi) {
            short8 a = *(short8*)&ua[mi][j];
            #pragma unroll
            for (int ni = 0; ni < 4; ++ni)
                acc[mi][ni] = __builtin_amdgcn_mfma_f32_16x16x32_bf16(a, b[ni], acc[mi][ni], 0, 0, 0);
        }
    }

    // kh=1 waves deposit partials
    if (kh == 1) {
        #pragma unroll
        for (int mi = 0; mi < 2; ++mi)
            #pragma unroll
            for (int ni = 0; ni < 4; ++ni)
                #pragma unroll
                for (int reg = 0; reg < 4; ++reg)
                    plds[wn][mi * 16 + ks * 4 + reg][ni * 16 + lr] = acc[mi][ni][reg];
    }
    __syncthreads();
    if (kh == 1) return;

    int col0 = wn * 64;
    const float third = 1.0f / 3.0f;
    float bb[4];
    #pragma unroll
    for (int ni = 0; ni < 4; ++ni) {
        int col = col0 + ni * 16 + lr;
        bb[ni] = bias[col] - third * cvec[col];
    }

    #pragma unroll
    for (int mi = 0; mi < 2; ++mi) {
        #pragma unroll
        for (int reg = 0; reg < 4; ++reg) {
            int rl = mi * 16 + ks * 4 + reg;
            int grow = row0 + rl;
            #pragma unroll
            for (int ni = 0; ni < 4; ++ni) {
                float v = acc[mi][ni][reg] + plds[wn][rl][ni * 16 + lr];
                out[(size_t)grow * DIM + col0 + ni * 16 + lr] = tanhf(v * third + bb[ni]);
            }
        }
    }
}

extern "C" void kernel_launch(void* const* d_in, const int* in_sizes, int n_in,
                              void* d_out, int out_size, void* d_ws, size_t ws_size,
                              hipStream_t stream) {
    const float* x        = (const float*)d_in[0];
    const float* r        = (const float*)d_in[1];
    const int*   ei       = (const int*)d_in[2];   // [2][800000]: rows then cols
    const int*   et       = (const int*)d_in[3];
    const float* w_in     = (const float*)d_in[4];
    const float* w_out    = (const float*)d_in[5];
    const float* w_loop   = (const float*)d_in[6];
    const float* w_rel    = (const float*)d_in[7];
    const float* loop_rel = (const float*)d_in[8];
    const float* bias     = (const float*)d_in[9];

    float* out   = (float*)d_out;            // 100000*128
    float* r_out = out + (size_t)N_ENT * DIM;

    // -------- workspace layout (~97 MB) --------
    unsigned short* aggf = (unsigned short*)d_ws;            // [2N*128] bf16 frag-order
    unsigned short* xb   = aggf + 2ull * N_ENT * DIM;        // [N][128] bf16 row-major
    unsigned short* wtf  = xb + (size_t)N_ENT * DIM;         // 8*12*64*8 bf16 frag-order
    unsigned short* rb16 = wtf + 8 * 12 * 64 * 8;            // [400][128] bf16
    unsigned* recs = (unsigned*)(rb16 + NUM_REL * DIM);      // [2N][CAP] x 4 B
    int*   cursor  = (int*)(recs + 2ull * N_ENT * CAP);      // 2N (doubles as deg)
    float* cvec    = (float*)(cursor + 2 * N_ENT);           // 128

    const int* rows = ei;
    const int* cols = ei + NUM_EDGES;

    hipMemsetAsync(cursor, 0, 2ull * N_ENT * sizeof(int), stream);

    mega_kernel<<<FB_REL, 256, 0, stream>>>(
        rows, cols, et, x, w_in, w_out, w_loop, r, loop_rel, w_rel,
        cursor, recs, (uint4*)xb, (uint4*)wtf, (uint4*)rb16, cvec, r_out);

    gather_agg_kernel<<<(2 * N_ENT * 16 + 255) / 256, 256, 0, stream>>>(
        cursor, recs, xb, rb16, (uint4*)aggf);

    mfma_gemm_kernel<<<N_ENT / 32, 256, 0, stream>>>(
        (const uint4*)aggf, xb, (const uint4*)wtf, bias, cvec, out);
}

// Round 17
// 145.404 us; speedup vs baseline: 1.1579x; 1.1579x over previous
//
#include <hip/hip_runtime.h>
#include <hip/hip_bf16.h>

#define N_ENT    100000
#define NUM_REL  400
#define DIM      128
#define NUM_EDGES 800000
#define E_HALF   400000
#define N_RB     6250          // N_ENT/16 rowblocks
#define CAP      24            // bucket capacity; P(Poisson(4) > 24) ~ 1.6e-12

using short8 = __attribute__((ext_vector_type(8))) short;
using f32x4  = __attribute__((ext_vector_type(4))) float;

__device__ __forceinline__ float bf_lo(unsigned u) { return __uint_as_float(u << 16); }
__device__ __forceinline__ float bf_hi(unsigned u) { return __uint_as_float(u & 0xffff0000u); }
__device__ __forceinline__ unsigned short f2bf(float f) {
    unsigned u = __float_as_uint(f);
    u = u + 0x7fffu + ((u >> 16) & 1u);   // RNE
    return (unsigned short)(u >> 16);
}
__device__ __forceinline__ unsigned pack2bf(float a, float b) {
    return (unsigned)f2bf(a) | ((unsigned)f2bf(b) << 16);
}

// ---------------- mega: fill (4 strided edges/thread) | xb (4 chunks/thread) | wtfrag | rb16 | cvec | rel ----------------
#define FILL_T  200192                 // 782*256 threads, 4 edges each
#define FB_FILL 782
#define FB_XB   (FB_FILL + 1563)       // 1563*256*4 chunks >= 1.6M
#define FB_WT   (FB_XB + 24)
#define FB_RB   (FB_WT + 25)
#define FB_CV   (FB_RB + 1)
#define FB_REL  (FB_CV + 200)
__global__ __launch_bounds__(256) void mega_kernel(const int* __restrict__ rows,
                                                   const int* __restrict__ cols,
                                                   const int* __restrict__ et,
                                                   const float* __restrict__ x,
                                                   const float* __restrict__ w_in,
                                                   const float* __restrict__ w_out,
                                                   const float* __restrict__ w_loop,
                                                   const float* __restrict__ r,
                                                   const float* __restrict__ loop_rel,
                                                   const float* __restrict__ w_rel,
                                                   int* __restrict__ cursor,
                                                   unsigned* __restrict__ recs,
                                                   uint4* __restrict__ xb4,
                                                   uint4* __restrict__ wtfrag,
                                                   uint4* __restrict__ rb16,
                                                   float* __restrict__ cvec,
                                                   float* __restrict__ r_out) {
    int b = blockIdx.x;
    int t = threadIdx.x;
    if (b < FB_FILL) {
        int base = b * 256 + t;
        #pragma unroll
        for (int k = 0; k < 4; ++k) {
            int e = base + k * FILL_T;
            if (e < NUM_EDGES) {
                int half = (e >= E_HALF) ? 1 : 0;
                int g = half * N_ENT + rows[e];
                int col = cols[e];
                int ty = et[e];
                int pos = atomicAdd(&cursor[g], 1);
                if (pos < CAP)
                    recs[(size_t)g * CAP + pos] = (unsigned)col | ((unsigned)ty << 17);
            }
        }
    } else if (b < FB_XB) {
        // 4 consecutive 64B-chunks per thread: 8 loads in flight, then 4 stores
        int i0 = ((b - FB_FILL) * 256 + t) * 4;
        float4 f[8];
        #pragma unroll
        for (int k = 0; k < 4; ++k) {
            int i = i0 + k;
            bool ok = i < N_ENT * 16;
            const float* p = x + (ok ? ((size_t)(i >> 4) * DIM + (i & 15) * 8) : 0);
            f[2 * k]     = *(const float4*)p;
            f[2 * k + 1] = *(const float4*)(p + 4);
        }
        #pragma unroll
        for (int k = 0; k < 4; ++k) {
            int i = i0 + k;
            if (i < N_ENT * 16) {
                uint4 o;
                o.x = pack2bf(f[2 * k].x, f[2 * k].y);
                o.y = pack2bf(f[2 * k].z, f[2 * k].w);
                o.z = pack2bf(f[2 * k + 1].x, f[2 * k + 1].y);
                o.w = pack2bf(f[2 * k + 1].z, f[2 * k + 1].w);
                xb4[i] = o;
            }
        }
    } else if (b < FB_WT) {
        int j = (b - FB_XB) * 256 + t;
        if (j < 8 * 12 * 64) {
            int lane = j & 63;
            int kb = (j >> 6) % 12;
            int nblk = j / 768;
            int n = nblk * 16 + (lane & 15);
            int s = kb >> 2;
            int klo = (kb & 3) * 32 + (lane >> 4) * 8;    // 0..127 within slice
            const float* W = (s == 0) ? w_in : (s == 1) ? w_out : w_loop;
            float v[8];
            #pragma unroll
            for (int e = 0; e < 8; ++e) v[e] = W[(klo + e) * DIM + n];
            uint4 o;
            o.x = pack2bf(v[0], v[1]);
            o.y = pack2bf(v[2], v[3]);
            o.z = pack2bf(v[4], v[5]);
            o.w = pack2bf(v[6], v[7]);
            wtfrag[j] = o;
        }
    } else if (b < FB_RB) {
        int k = (b - FB_WT) * 256 + t;
        if (k < NUM_REL * 16) {
            const float* p = r + (size_t)(k >> 4) * DIM + (k & 15) * 8;
            float4 f0 = *(const float4*)p;
            float4 f1 = *(const float4*)(p + 4);
            uint4 o;
            o.x = pack2bf(f0.x, f0.y);
            o.y = pack2bf(f0.z, f0.w);
            o.z = pack2bf(f1.x, f1.y);
            o.w = pack2bf(f1.z, f1.w);
            rb16[k] = o;
        }
    } else if (b < FB_CV) {
        if (t < 128) {
            float acc = 0.0f;
            #pragma unroll 8
            for (int k = 0; k < DIM; ++k)
                acc += loop_rel[k] * w_loop[k * DIM + t];
            cvec[t] = acc;
        }
    } else {
        int row = (b - FB_CV) * 2 + (t >> 7);
        int col = t & 127;
        const float* rr = r + (size_t)row * DIM;
        float acc = 0.0f;
        #pragma unroll 8
        for (int k = 0; k < DIM; ++k)
            acc += rr[k] * w_rel[k * DIM + col];
        r_out[(size_t)row * DIM + col] = acc;
    }
}

// ---------------- gather-aggregate -> aggfrag (16 lanes/segment, 4-edge unroll) ----------------
#define ACC8(X, V, NRM)                                        \
    acc[0] += (NRM) * (bf_lo((X).x) - bf_lo((V).x));           \
    acc[1] += (NRM) * (bf_hi((X).x) - bf_hi((V).x));           \
    acc[2] += (NRM) * (bf_lo((X).y) - bf_lo((V).y));           \
    acc[3] += (NRM) * (bf_hi((X).y) - bf_hi((V).y));           \
    acc[4] += (NRM) * (bf_lo((X).z) - bf_lo((V).z));           \
    acc[5] += (NRM) * (bf_hi((X).z) - bf_hi((V).z));           \
    acc[6] += (NRM) * (bf_lo((X).w) - bf_lo((V).w));           \
    acc[7] += (NRM) * (bf_hi((X).w) - bf_hi((V).w));

__global__ __launch_bounds__(256) void gather_agg_kernel(const int* __restrict__ cursor,
                                                         const unsigned* __restrict__ recs,
                                                         const unsigned short* __restrict__ xb,
                                                         const unsigned short* __restrict__ rb16,
                                                         uint4* __restrict__ aggfrag) {
    int gid = blockIdx.x * 256 + threadIdx.x;
    int g = gid >> 4;
    if (g >= 2 * N_ENT) return;
    int c = gid & 15;                    // lane covers 16 B = 8 bf16 (k = c*8..c*8+7)
    int dg = cursor[g];
    int hb = (g >= N_ENT) ? N_ENT : 0;   // deg base for this half
    float acc[8] = {0.f, 0.f, 0.f, 0.f, 0.f, 0.f, 0.f, 0.f};
    if (dg > 0) {
        int dgc = dg < CAP ? dg : CAP;
        float dgi = rsqrtf((float)dg);
        const unsigned* rb = recs + (size_t)g * CAP;
        int e = 0;
        for (; e + 4 <= dgc; e += 4) {
            unsigned r0 = rb[e], r1 = rb[e + 1], r2 = rb[e + 2], r3 = rb[e + 3];
            int c0 = r0 & 0x1ffff, t0 = r0 >> 17;
            int c1 = r1 & 0x1ffff, t1 = r1 >> 17;
            int c2 = r2 & 0x1ffff, t2 = r2 >> 17;
            int c3 = r3 & 0x1ffff, t3 = r3 >> 17;
            int d0 = cursor[hb + c0];
            int d1 = cursor[hb + c1];
            int d2 = cursor[hb + c2];
            int d3 = cursor[hb + c3];
            uint4 x0 = ((const uint4*)(xb + (size_t)c0 * DIM))[c];
            uint4 v0 = ((const uint4*)(rb16 + (size_t)t0 * DIM))[c];
            uint4 x1 = ((const uint4*)(xb + (size_t)c1 * DIM))[c];
            uint4 v1 = ((const uint4*)(rb16 + (size_t)t1 * DIM))[c];
            uint4 x2 = ((const uint4*)(xb + (size_t)c2 * DIM))[c];
            uint4 v2 = ((const uint4*)(rb16 + (size_t)t2 * DIM))[c];
            uint4 x3 = ((const uint4*)(xb + (size_t)c3 * DIM))[c];
            uint4 v3 = ((const uint4*)(rb16 + (size_t)t3 * DIM))[c];
            float n0 = (d0 > 0) ? dgi * rsqrtf((float)d0) : 0.0f;
            float n1 = (d1 > 0) ? dgi * rsqrtf((float)d1) : 0.0f;
            float n2 = (d2 > 0) ? dgi * rsqrtf((float)d2) : 0.0f;
            float n3 = (d3 > 0) ? dgi * rsqrtf((float)d3) : 0.0f;
            ACC8(x0, v0, n0)
            ACC8(x1, v1, n1)
            ACC8(x2, v2, n2)
            ACC8(x3, v3, n3)
        }
        for (; e < dgc; ++e) {
            unsigned rA = rb[e];
            int cA = rA & 0x1ffff, tA = rA >> 17;
            int dA = cursor[hb + cA];
            uint4 xA = ((const uint4*)(xb + (size_t)cA * DIM))[c];
            uint4 vA = ((const uint4*)(rb16 + (size_t)tA * DIM))[c];
            float nA = (dA > 0) ? dgi * rsqrtf((float)dA) : 0.0f;
            ACC8(xA, vA, nA)
        }
    }
    uint4 o;
    o.x = pack2bf(acc[0], acc[1]);
    o.y = pack2bf(acc[2], acc[3]);
    o.z = pack2bf(acc[4], acc[5]);
    o.w = pack2bf(acc[6], acc[7]);
    // fragment-order store: rowblk=g>>4, kq=c>>2, ksub=c&3, lr=g&15
    aggfrag[(((g >> 4) * 4 + (c >> 2)) * 64) + (c & 3) * 16 + (g & 15)] = o;
}

// ---------------- MFMA GEMM, fragment-direct, split-K2, hoisted A-loads ----------------
// out = tanh((aggA@Win + aggB@Wout + x@Wloop - cvec)/3 + bias)
// M=100000, N=128, K=384. Block = 32 rows x 128 cols, 4 waves (wn, kh).
__global__ __launch_bounds__(256) void mfma_gemm_kernel(const uint4* __restrict__ aggfrag,
                                                        const unsigned short* __restrict__ xb,
                                                        const uint4* __restrict__ wtfrag,
                                                        const float* __restrict__ bias,
                                                        const float* __restrict__ cvec,
                                                        float* __restrict__ out) {
    __shared__ float plds[2][32][65];      // 16.6 KB, stride-65 rows (bank-safe)

    int tid = threadIdx.x;
    int wave = tid >> 6;
    int lane = tid & 63;
    int wn = wave & 1;                     // col half
    int kh = wave >> 1;                    // K half
    int lr = lane & 15;
    int ks = lane >> 4;                    // 0..3
    int rbb = blockIdx.x * 2;              // 2 rowblocks of 16 (exact: 3125*32=100000)
    int row0 = blockIdx.x * 32;

    // ---- hoist ALL A-fragment loads (12 uint4, statically indexed) ----
    uint4 ua[2][6];
    #pragma unroll
    for (int j = 0; j < 6; ++j) {
        int kb = kh * 6 + j;
        int s = kb >> 2, kq = kb & 3;      // wave-uniform
        #pragma unroll
        for (int mi = 0; mi < 2; ++mi) {
            if (s < 2) {
                ua[mi][j] = aggfrag[((size_t)(rbb + mi + s * N_RB) * 4 + kq) * 64 + lane];
            } else {
                int row = (rbb + mi) * 16 + lr;
                ua[mi][j] = *(const uint4*)(xb + (size_t)row * DIM + kq * 32 + ks * 8);
            }
        }
    }

    f32x4 acc[2][4];
    #pragma unroll
    for (int mi = 0; mi < 2; ++mi)
        #pragma unroll
        for (int ni = 0; ni < 4; ++ni)
            acc[mi][ni] = (f32x4){0.f, 0.f, 0.f, 0.f};

    #pragma unroll
    for (int j = 0; j < 6; ++j) {
        int kb = kh * 6 + j;
        short8 b[4];
        #pragma unroll
        for (int ni = 0; ni < 4; ++ni) {
            uint4 u = wtfrag[((wn * 4 + ni) * 12 + kb) * 64 + lane];
            b[ni] = *(short8*)&u;
        }
        #pragma unroll
        for (int mi = 0; mi < 2; ++mi) {
            short8 a = *(short8*)&ua[mi][j];
            #pragma unroll
            for (int ni = 0; ni < 4; ++ni)
                acc[mi][ni] = __builtin_amdgcn_mfma_f32_16x16x32_bf16(a, b[ni], acc[mi][ni], 0, 0, 0);
        }
    }

    // kh=1 waves deposit partials
    if (kh == 1) {
        #pragma unroll
        for (int mi = 0; mi < 2; ++mi)
            #pragma unroll
            for (int ni = 0; ni < 4; ++ni)
                #pragma unroll
                for (int reg = 0; reg < 4; ++reg)
                    plds[wn][mi * 16 + ks * 4 + reg][ni * 16 + lr] = acc[mi][ni][reg];
    }
    __syncthreads();
    if (kh == 1) return;

    int col0 = wn * 64;
    const float third = 1.0f / 3.0f;
    float bb[4];
    #pragma unroll
    for (int ni = 0; ni < 4; ++ni) {
        int col = col0 + ni * 16 + lr;
        bb[ni] = bias[col] - third * cvec[col];
    }

    #pragma unroll
    for (int mi = 0; mi < 2; ++mi) {
        #pragma unroll
        for (int reg = 0; reg < 4; ++reg) {
            int rl = mi * 16 + ks * 4 + reg;
            int grow = row0 + rl;
            #pragma unroll
            for (int ni = 0; ni < 4; ++ni) {
                float v = acc[mi][ni][reg] + plds[wn][rl][ni * 16 + lr];
                out[(size_t)grow * DIM + col0 + ni * 16 + lr] = tanhf(v * third + bb[ni]);
            }
        }
    }
}

extern "C" void kernel_launch(void* const* d_in, const int* in_sizes, int n_in,
                              void* d_out, int out_size, void* d_ws, size_t ws_size,
                              hipStream_t stream) {
    const float* x        = (const float*)d_in[0];
    const float* r        = (const float*)d_in[1];
    const int*   ei       = (const int*)d_in[2];   // [2][800000]: rows then cols
    const int*   et       = (const int*)d_in[3];
    const float* w_in     = (const float*)d_in[4];
    const float* w_out    = (const float*)d_in[5];
    const float* w_loop   = (const float*)d_in[6];
    const float* w_rel    = (const float*)d_in[7];
    const float* loop_rel = (const float*)d_in[8];
    const float* bias     = (const float*)d_in[9];

    float* out   = (float*)d_out;            // 100000*128
    float* r_out = out + (size_t)N_ENT * DIM;

    // -------- workspace layout (~97 MB) --------
    unsigned short* aggf = (unsigned short*)d_ws;            // [2N*128] bf16 frag-order
    unsigned short* xb   = aggf + 2ull * N_ENT * DIM;        // [N][128] bf16 row-major
    unsigned short* wtf  = xb + (size_t)N_ENT * DIM;         // 8*12*64*8 bf16 frag-order
    unsigned short* rb16 = wtf + 8 * 12 * 64 * 8;            // [400][128] bf16
    unsigned* recs = (unsigned*)(rb16 + NUM_REL * DIM);      // [2N][CAP] x 4 B
    int*   cursor  = (int*)(recs + 2ull * N_ENT * CAP);      // 2N (doubles as deg)
    float* cvec    = (float*)(cursor + 2 * N_ENT);           // 128

    const int* rows = ei;
    const int* cols = ei + NUM_EDGES;

    hipMemsetAsync(cursor, 0, 2ull * N_ENT * sizeof(int), stream);

    mega_kernel<<<FB_REL, 256, 0, stream>>>(
        rows, cols, et, x, w_in, w_out, w_loop, r, loop_rel, w_rel,
        cursor, recs, (uint4*)xb, (uint4*)wtf, (uint4*)rb16, cvec, r_out);

    gather_agg_kernel<<<(2 * N_ENT * 16 + 255) / 256, 256, 0, stream>>>(
        cursor, recs, xb, rb16, (uint4*)aggf);

    mfma_gemm_kernel<<<N_ENT / 32, 256, 0, stream>>>(
        (const uint4*)aggf, xb, (const uint4*)wtf, bias, cvec, out);
}